// Round 2
// baseline (682.566 us; speedup 1.0000x reference)
//
#include <hip/hip_runtime.h>
#include <hip/hip_bf16.h>
#include <stdint.h>

// ---------------- constants ----------------
// B=1, N=768, C_A=768, C_S=384, C_Z=128, H=16, C_HID=48, N_TRANS=2

typedef __bf16 bf16x8 __attribute__((ext_vector_type(8)));
typedef float  f32x4  __attribute__((ext_vector_type(4)));

#define DEVI __device__ __forceinline__

DEVI uint16_t f2b(float f){ __hip_bfloat16 h = __float2bfloat16(f); return __builtin_bit_cast(uint16_t, h); }
DEVI float    b2f(uint16_t u){ return __bfloat162float(__builtin_bit_cast(__hip_bfloat16, u)); }
DEVI float    sigm(float x){ return 1.0f/(1.0f + __expf(-x)); }

DEVI f32x4 MFMA(uint4 a, uint4 b, f32x4 c){
  return __builtin_amdgcn_mfma_f32_16x16x32_bf16(
      __builtin_bit_cast(bf16x8, a), __builtin_bit_cast(bf16x8, b), c, 0, 0, 0);
}

// ---------------- workspace layout (bytes, all 256-aligned) ----------------
constexpr size_t SZ_BT_ADA   = (size_t)1536*384*2;
constexpr size_t OFF_BT_ADA_ATTN = 0;
constexpr size_t OFF_BT_ADA_TR   = OFF_BT_ADA_ATTN + SZ_BT_ADA;
constexpr size_t OFF_BT_OUTGATE  = OFF_BT_ADA_TR   + SZ_BT_ADA;
constexpr size_t OFF_BT_QKVG     = OFF_BT_OUTGATE  + SZ_BT_ADA;
constexpr size_t OFF_BT_WO       = OFF_BT_QKVG + (size_t)3072*768*2;
constexpr size_t OFF_BT_W12      = OFF_BT_WO   + (size_t)768*768*2;
constexpr size_t OFF_BT_TRWO     = OFF_BT_W12  + (size_t)3072*768*2;
constexpr size_t OFF_WBGT        = OFF_BT_TRWO + (size_t)768*1536*2;
constexpr size_t OFF_ZCOL        = OFF_WBGT + 4096;
constexpr size_t OFF_OGB         = OFF_ZCOL + 256;
constexpr size_t OFF_SBF         = OFF_OGB + 6144;
constexpr size_t OFF_SLNA        = OFF_SBF  + (size_t)768*384*2;
constexpr size_t OFF_SLNT        = OFF_SLNA + (size_t)768*384*2;
constexpr size_t OFF_ALNRAW      = OFF_SLNT + (size_t)768*384*2;
constexpr size_t OFF_GATEOUT     = OFF_ALNRAW + (size_t)768*768*4;
constexpr size_t OFF_GS          = OFF_GATEOUT + (size_t)768*1536*4;
constexpr size_t OFF_ALNBF       = OFF_GS + (size_t)768*1536*4;
constexpr size_t OFF_QKVG        = OFF_ALNBF + (size_t)768*768*2;
constexpr size_t OFF_QP          = OFF_QKVG + (size_t)768*3072*4;
constexpr size_t OFF_KP          = OFF_QP + (size_t)16*768*64*2;
constexpr size_t OFF_VT          = OFF_KP + (size_t)16*768*64*2;
constexpr size_t OFF_BIAS        = OFF_VT + (size_t)16*64*768*2;   // later reused as hid_bf16
constexpr size_t OFF_SP          = OFF_BIAS + (size_t)16*768*768*2;
constexpr size_t OFF_OBF         = OFF_SP + (size_t)16*768*768*2;
constexpr size_t OFF_AMID        = OFF_OBF + (size_t)768*768*2;

// ---------------- weight transpose/convert fp32 -> bf16 B^T ----------------
struct CvtArgs {
  const float* src[14];
  uint16_t*    dst[14];
  int K[14], N[14];
  int prefix[15];
};

__global__ __launch_bounds__(256) void k_cvt(CvtArgs a){
  int bid = blockIdx.x;
  int ti = 0;
  while (ti < 13 && bid >= a.prefix[ti+1]) ti++;
  int local = bid - a.prefix[ti];
  int K = a.K[ti], N = a.N[ti];
  int tN = N >> 5;
  int n0 = (local % tN) << 5, k0 = (local / tN) << 5;
  __shared__ float lds[32][33];
  const float* src = a.src[ti];
  uint16_t* dst = a.dst[ti];
  int t = threadIdx.x;
  int c = t & 31, r0 = t >> 5;
  #pragma unroll
  for (int i = 0; i < 4; i++){
    int kk = r0 + 8*i;
    lds[kk][c] = src[(size_t)(k0+kk)*N + n0 + c];
  }
  __syncthreads();
  #pragma unroll
  for (int i = 0; i < 4; i++){
    int nn = r0 + 8*i;
    dst[(size_t)(n0+nn)*K + k0 + c] = f2b(lds[c][nn]);
  }
}

// ---------------- prep: LN(s), gate-bias concat, wb*g prep ----------------
__global__ __launch_bounds__(128) void k_prep(
    const float* s, const float* g_attn, const float* g_tr,
    const float* attn_ogb, const float* tr_ogb,
    const float* z_g, const float* z_b, const float* wb,
    uint16_t* s_bf, uint16_t* sln_a, uint16_t* sln_t,
    float* ogb, uint16_t* wbgt, float* zcol)
{
  int b = blockIdx.x, t = threadIdx.x;
  if (b < 768){
    const float* row = s + (size_t)b*384;
    float x0 = row[t], x1 = row[t+128], x2 = row[t+256];
    float sm = x0+x1+x2, sq = x0*x0+x1*x1+x2*x2;
    #pragma unroll
    for (int off = 32; off; off >>= 1){ sm += __shfl_xor(sm, off, 64); sq += __shfl_xor(sq, off, 64); }
    __shared__ float rs_[2], rq_[2];
    int w = t >> 6;
    if ((t & 63) == 0){ rs_[w] = sm; rq_[w] = sq; }
    __syncthreads();
    float S = rs_[0]+rs_[1], Q = rq_[0]+rq_[1];
    float mu = S * (1.f/384.f);
    float var = Q * (1.f/384.f) - mu*mu;
    float rstd = rsqrtf(var + 1e-5f);
    float xs[3] = {x0, x1, x2};
    #pragma unroll
    for (int i = 0; i < 3; i++){
      int ci = t + 128*i;
      float ln = (xs[i] - mu) * rstd;
      s_bf [(size_t)b*384 + ci] = f2b(xs[i]);
      sln_a[(size_t)b*384 + ci] = f2b(ln * g_attn[ci]);
      sln_t[(size_t)b*384 + ci] = f2b(ln * g_tr[ci]);
    }
  } else if (b == 768){
    for (int i = t; i < 1536; i += 128)
      ogb[i] = (i < 768) ? attn_ogb[i] : tr_ogb[i-768];
  } else {
    for (int i = t; i < 2048; i += 128){
      int h = i >> 7, c = i & 127;
      wbgt[i] = f2b(z_g[c] * wb[c*16 + h]);
    }
    if (t < 16){
      float cs = 0.f, cn = 0.f;
      for (int c = 0; c < 128; c++){ cs += z_g[c]*wb[c*16+t]; cn += z_b[c]*wb[c*16+t]; }
      zcol[t] = cs; zcol[16+t] = cn;
    }
  }
}

// ---------------- row LayerNorm over 768 (no affine) ----------------
__global__ __launch_bounds__(256) void k_ln768(const float* in, float* out){
  int b = blockIdx.x, t = threadIdx.x;
  const float* row = in + (size_t)b*768;
  float x0 = row[t], x1 = row[t+256], x2 = row[t+512];
  float sm = x0+x1+x2, sq = x0*x0+x1*x1+x2*x2;
  #pragma unroll
  for (int off = 32; off; off >>= 1){ sm += __shfl_xor(sm, off, 64); sq += __shfl_xor(sq, off, 64); }
  __shared__ float rs_[4], rq_[4];
  int w = t >> 6;
  if ((t & 63) == 0){ rs_[w] = sm; rq_[w] = sq; }
  __syncthreads();
  float S = rs_[0]+rs_[1]+rs_[2]+rs_[3], Q = rq_[0]+rq_[1]+rq_[2]+rq_[3];
  float mu = S*(1.f/768.f), var = Q*(1.f/768.f) - mu*mu, rstd = rsqrtf(var + 1e-5f);
  float* orow = out + (size_t)b*768;
  orow[t]     = (x0-mu)*rstd;
  orow[t+256] = (x1-mu)*rstd;
  orow[t+512] = (x2-mu)*rstd;
}

// ---------------- generic bf16 MFMA GEMM: C = A[MxK] * B, B given as BT[NxK] ----------------
// modes: 0 fp32 out, 1 bf16 out, 2 sigmoid(x+bias[col]) fp32,
//        4 resid + mask[row]*gate*x (fp32), 5 resid + gate*x (fp32)
__global__ __launch_bounds__(256) void k_gemm(
    const uint16_t* __restrict__ A, const uint16_t* __restrict__ BT,
    int M, int N, int K,
    float* outF, uint16_t* outB, int mode,
    const float* bias, const float* gate, int gateLd, int gateOff,
    const float* resid, const int* mask)
{
  constexpr int SA = 40;
  __shared__ uint16_t As[64*SA], Bs[64*SA];
  int t = threadIdx.x;
  int n0 = blockIdx.x*64, m0 = blockIdx.y*64;
  int w = t >> 6, lane = t & 63, mm = lane & 15, q = lane >> 4;
  f32x4 zz = {0.f, 0.f, 0.f, 0.f};
  f32x4 acc[4] = {zz, zz, zz, zz};
  int r = t >> 2, c4 = t & 3;
  const uint4* Ag = (const uint4*)(A + (size_t)(m0 + r)*K) + c4;
  const uint4* Bg = (const uint4*)(BT + (size_t)(n0 + r)*K) + c4;
  for (int k0 = 0; k0 < K; k0 += 32){
    *(uint4*)&As[r*SA + c4*8] = Ag[k0 >> 3];
    *(uint4*)&Bs[r*SA + c4*8] = Bg[k0 >> 3];
    __syncthreads();
    uint4 av = *(const uint4*)&As[(16*w + mm)*SA + q*8];
    #pragma unroll
    for (int j = 0; j < 4; j++){
      uint4 bv = *(const uint4*)&Bs[(16*j + mm)*SA + q*8];
      acc[j] = MFMA(av, bv, acc[j]);
    }
    __syncthreads();
  }
  #pragma unroll
  for (int j = 0; j < 4; j++){
    #pragma unroll
    for (int rr = 0; rr < 4; rr++){
      int row = m0 + 16*w + q*4 + rr;
      int col = n0 + 16*j + mm;
      float v = acc[j][rr];
      size_t oi = (size_t)row*N + col;
      if (mode == 0)      outF[oi] = v;
      else if (mode == 1) outB[oi] = f2b(v);
      else if (mode == 2) outF[oi] = sigm(v + bias[col]);
      else if (mode == 5) outF[oi] = resid[oi] + gate[(size_t)row*gateLd + gateOff + col]*v;
      else {
        float mf = (float)mask[row];
        outF[oi] = resid[oi] + mf * gate[(size_t)row*gateLd + gateOff + col] * v;
      }
    }
  }
}

// ---------------- z -> pair bias: bias[h][i][j] = LN(z[i,j,:])*g+b @ wb ----------------
__global__ __launch_bounds__(256) void k_zbias(
    const float* __restrict__ z, const uint16_t* __restrict__ wbgt_g,
    const float* __restrict__ zcol, uint16_t* __restrict__ bias_g)
{
  __shared__ uint16_t zb[64*128];     // 64 pairs x 128 ch bf16
  __shared__ uint16_t wbt[16*128];    // [h][c]
  __shared__ float mu_s[64], rs_s[64];
  __shared__ uint16_t Sout[16*72];
  int t = threadIdx.x;
  size_t P0 = (size_t)blockIdx.y*768 + (size_t)blockIdx.x*64;
  // wbt is 16*128 bf16 = 4096 B = 256 uint4: ALL 256 threads copy one uint4.
  // (Round-1 bug: `if (t<128)` left half of wbt uninitialized -> NaN bias -> NaN softmax.)
  ((uint4*)wbt)[t] = ((const uint4*)wbgt_g)[t];
  int p = t >> 2, qq = t & 3;
  const float4* zp = (const float4*)(z + (P0 + p)*128) + qq*8;
  float s1 = 0.f, s2 = 0.f;
  uint32_t lb[16];
  #pragma unroll
  for (int it = 0; it < 8; it++){
    float4 v = zp[it];
    s1 += v.x + v.y + v.z + v.w;
    s2 += v.x*v.x + v.y*v.y + v.z*v.z + v.w*v.w;
    lb[2*it]   = (uint32_t)f2b(v.x) | ((uint32_t)f2b(v.y) << 16);
    lb[2*it+1] = (uint32_t)f2b(v.z) | ((uint32_t)f2b(v.w) << 16);
  }
  uint4* zb4 = (uint4*)zb;
  #pragma unroll
  for (int kk = 0; kk < 4; kk++)
    zb4[p*16 + qq*4 + kk] = ((uint4*)lb)[kk];
  s1 += __shfl_xor(s1, 1, 64); s1 += __shfl_xor(s1, 2, 64);
  s2 += __shfl_xor(s2, 1, 64); s2 += __shfl_xor(s2, 2, 64);
  if (qq == 0){
    float mu = s1 * (1.f/128.f);
    mu_s[p] = mu;
    rs_s[p] = rsqrtf(s2*(1.f/128.f) - mu*mu + 1e-5f);
  }
  __syncthreads();
  int w = t >> 6, lane = t & 63, hh = lane & 15, q = lane >> 4;
  float cs = zcol[hh], cn = zcol[16 + hh];
  f32x4 acc = {0.f, 0.f, 0.f, 0.f};
  const uint4* wbt4 = (const uint4*)wbt;
  #pragma unroll
  for (int kc = 0; kc < 4; kc++){
    uint4 av = zb4[(16*w + hh)*16 + kc*4 + q];
    uint4 bv = wbt4[hh*16 + kc*4 + q];
    acc = MFMA(av, bv, acc);
  }
  #pragma unroll
  for (int rr = 0; rr < 4; rr++){
    int pl = 16*w + q*4 + rr;
    float val = rs_s[pl]*(acc[rr] - mu_s[pl]*cs) + cn;
    Sout[hh*72 + pl] = f2b(val);
  }
  __syncthreads();
  int h2 = t >> 4, p2 = (t & 15)*4;
  uint2 v2 = *(uint2*)&Sout[h2*72 + p2];
  *(uint2*)(bias_g + (size_t)h2*589824 + P0 + p2) = v2;
}

// ---------------- split qkvg -> padded q,k [h][n][64] and v^T [h][64][n] ----------------
__global__ __launch_bounds__(256) void k_trans(
    const float* __restrict__ qkvg, const float* __restrict__ bq,
    uint16_t* qp, uint16_t* kp, uint16_t* vt)
{
  int h = blockIdx.y, n0 = blockIdx.x*64, t = threadIdx.x;
  __shared__ uint16_t vbuf[64*72];
  int c = t & 63, r0 = t >> 6;
  const float scale = 0.14433756729740643f;  // 1/sqrt(48)
  for (int r = r0; r < 64; r += 4){
    size_t base = (size_t)(n0 + r)*3072;
    float qv = 0.f, kv = 0.f, vv = 0.f;
    if (c < 48){
      int cc = h*48 + c;
      qv = (qkvg[base + cc] + bq[cc]) * scale;
      kv = qkvg[base + 768 + cc];
      vv = qkvg[base + 1536 + cc];
    }
    size_t oi = ((size_t)h*768 + n0 + r)*64 + c;
    qp[oi] = f2b(qv);
    kp[oi] = f2b(kv);
    vbuf[c*72 + r] = f2b(vv);
  }
  __syncthreads();
  int cc = t >> 2, rb = (t & 3)*16;
  uint16_t* dst = vt + ((size_t)h*64 + cc)*768 + n0 + rb;
  *(uint4*)dst       = *(uint4*)&vbuf[cc*72 + rb];
  *(uint4*)(dst + 8) = *(uint4*)&vbuf[cc*72 + rb + 8];
}

// ---------------- logits = q.k^T + bias + mask -> bf16 scores ----------------
__global__ __launch_bounds__(256) void k_logits(
    const uint16_t* __restrict__ qp, const uint16_t* __restrict__ kp,
    const uint16_t* __restrict__ bias_g, const int* __restrict__ mask,
    uint16_t* __restrict__ SP)
{
  int h = blockIdx.z, q0 = blockIdx.y*64, k0 = blockIdx.x*64;
  constexpr int SA = 72;
  __shared__ uint16_t Qs[64*SA], Ks[64*SA];
  int t = threadIdx.x;
  int r = t >> 2, c4 = t & 3;
  const uint4* Qg = (const uint4*)(qp + ((size_t)h*768 + q0 + r)*64);
  const uint4* Kg = (const uint4*)(kp + ((size_t)h*768 + k0 + r)*64);
  *(uint4*)&Qs[r*SA + c4*8]       = Qg[c4];
  *(uint4*)&Qs[r*SA + (c4+4)*8]   = Qg[c4+4];
  *(uint4*)&Ks[r*SA + c4*8]       = Kg[c4];
  *(uint4*)&Ks[r*SA + (c4+4)*8]   = Kg[c4+4];
  __syncthreads();
  int w = t >> 6, lane = t & 63, mm = lane & 15, q = lane >> 4;
  f32x4 zz = {0.f,0.f,0.f,0.f};
  f32x4 acc[4] = {zz, zz, zz, zz};
  #pragma unroll
  for (int kc = 0; kc < 2; kc++){
    uint4 av = *(const uint4*)&Qs[(16*w + mm)*SA + kc*32 + q*8];
    #pragma unroll
    for (int j = 0; j < 4; j++){
      uint4 bv = *(const uint4*)&Ks[(16*j + mm)*SA + kc*32 + q*8];
      acc[j] = MFMA(av, bv, acc[j]);
    }
  }
  #pragma unroll
  for (int j = 0; j < 4; j++){
    #pragma unroll
    for (int rr = 0; rr < 4; rr++){
      int row = q0 + 16*w + q*4 + rr;
      int col = k0 + 16*j + mm;
      size_t bi = (size_t)h*589824 + (size_t)row*768 + col;
      float v = acc[j][rr] + b2f(bias_g[bi]) + ((float)mask[col] - 1.f)*1e9f;
      SP[bi] = f2b(v);
    }
  }
}

// ---------------- in-place row softmax over 768 ----------------
__global__ __launch_bounds__(256) void k_softmax(uint16_t* SP){
  size_t base = (size_t)blockIdx.x * 768;
  int t = threadIdx.x;
  float x0 = b2f(SP[base+t]), x1 = b2f(SP[base+t+256]), x2 = b2f(SP[base+t+512]);
  float mx = fmaxf(x0, fmaxf(x1, x2));
  #pragma unroll
  for (int off = 32; off; off >>= 1) mx = fmaxf(mx, __shfl_xor(mx, off, 64));
  __shared__ float rm[4], rsum[4];
  int w = t >> 6;
  if ((t & 63) == 0) rm[w] = mx;
  __syncthreads();
  mx = fmaxf(fmaxf(rm[0], rm[1]), fmaxf(rm[2], rm[3]));
  float e0 = __expf(x0 - mx), e1 = __expf(x1 - mx), e2 = __expf(x2 - mx);
  float sm = e0 + e1 + e2;
  #pragma unroll
  for (int off = 32; off; off >>= 1) sm += __shfl_xor(sm, off, 64);
  if ((t & 63) == 0) rsum[w] = sm;
  __syncthreads();
  sm = rsum[0]+rsum[1]+rsum[2]+rsum[3];
  float inv = 1.f / sm;
  SP[base+t]     = f2b(e0*inv);
  SP[base+t+256] = f2b(e1*inv);
  SP[base+t+512] = f2b(e2*inv);
}

// ---------------- o = (P @ v) * sigmoid(g), written as [n][h*48+c] bf16 ----------------
__global__ __launch_bounds__(256) void k_pv(
    const uint16_t* __restrict__ SP, const uint16_t* __restrict__ vt,
    const float* __restrict__ qkvg, uint16_t* __restrict__ obf)
{
  int h = blockIdx.y, q0 = blockIdx.x*64;
  constexpr int SA = 40;
  __shared__ uint16_t Ps[64*SA], Vs[64*SA];
  int t = threadIdx.x;
  int r = t >> 2, c4 = t & 3;
  int w = t >> 6, lane = t & 63, mm = lane & 15, q = lane >> 4;
  const uint16_t* Pbase = SP + (size_t)h*589824;
  const uint16_t* Vbase = vt + (size_t)h*64*768;
  f32x4 zz = {0.f,0.f,0.f,0.f};
  f32x4 acc[3] = {zz, zz, zz};
  for (int k0 = 0; k0 < 768; k0 += 32){
    *(uint4*)&Ps[r*SA + c4*8] = *((const uint4*)(Pbase + (size_t)(q0 + r)*768 + k0) + c4);
    *(uint4*)&Vs[r*SA + c4*8] = *((const uint4*)(Vbase + (size_t)r*768 + k0) + c4);
    __syncthreads();
    uint4 av = *(const uint4*)&Ps[(16*w + mm)*SA + q*8];
    #pragma unroll
    for (int j = 0; j < 3; j++){
      uint4 bv = *(const uint4*)&Vs[(16*j + mm)*SA + q*8];
      acc[j] = MFMA(av, bv, acc[j]);
    }
    __syncthreads();
  }
  #pragma unroll
  for (int j = 0; j < 3; j++){
    #pragma unroll
    for (int rr = 0; rr < 4; rr++){
      int col = 16*j + mm;
      if (col < 48){
        int row = q0 + 16*w + q*4 + rr;
        float g = qkvg[(size_t)row*3072 + 2304 + h*48 + col];
        obf[(size_t)row*768 + h*48 + col] = f2b(acc[j][rr] * sigm(g));
      }
    }
  }
}

// ---------------- adaLN combine: sigmoid(gs[:, :768]+b)*a_ln + gs[:, 768:] -> bf16 ----------------
__global__ __launch_bounds__(256) void k_adaln(
    const float* __restrict__ gs, const float* __restrict__ gb,
    const float* __restrict__ alnraw, uint16_t* __restrict__ aln)
{
  int idx4 = blockIdx.x*256 + threadIdx.x;
  int row = idx4 / 192;
  int c4 = (idx4 % 192)*4;
  float4 g4 = *(const float4*)(gs + (size_t)row*1536 + c4);
  float4 s4 = *(const float4*)(gs + (size_t)row*1536 + 768 + c4);
  float4 a4 = *(const float4*)(alnraw + (size_t)row*768 + c4);
  float4 b4 = *(const float4*)(gb + c4);
  uint32_t lo = (uint32_t)f2b(sigm(g4.x + b4.x)*a4.x + s4.x)
              | ((uint32_t)f2b(sigm(g4.y + b4.y)*a4.y + s4.y) << 16);
  uint32_t hi = (uint32_t)f2b(sigm(g4.z + b4.z)*a4.z + s4.z)
              | ((uint32_t)f2b(sigm(g4.w + b4.w)*a4.w + s4.w) << 16);
  uint2 uv; uv.x = lo; uv.y = hi;
  *(uint2*)(aln + (size_t)row*768 + c4) = uv;
}

// ---------------- SwiGLU: silu(h1)*h2 -> bf16 ----------------
__global__ __launch_bounds__(256) void k_silu(const float* __restrict__ h12, uint16_t* __restrict__ hid){
  int idx4 = blockIdx.x*256 + threadIdx.x;
  int row = idx4 / 384;
  int c4 = (idx4 % 384)*4;
  float4 x1 = *(const float4*)(h12 + (size_t)row*3072 + c4);
  float4 x2 = *(const float4*)(h12 + (size_t)row*3072 + 1536 + c4);
  uint32_t lo = (uint32_t)f2b(x1.x*sigm(x1.x)*x2.x)
              | ((uint32_t)f2b(x1.y*sigm(x1.y)*x2.y) << 16);
  uint32_t hi = (uint32_t)f2b(x1.z*sigm(x1.z)*x2.z)
              | ((uint32_t)f2b(x1.w*sigm(x1.w)*x2.w) << 16);
  uint2 uv; uv.x = lo; uv.y = hi;
  *(uint2*)(hid + (size_t)row*1536 + c4) = uv;
}

// ---------------- host launcher ----------------
extern "C" void kernel_launch(void* const* d_in, const int* in_sizes, int n_in,
                              void* d_out, int out_size, void* d_ws, size_t ws_size,
                              hipStream_t stream)
{
  const float* a            = (const float*)d_in[0];
  const float* s            = (const float*)d_in[1];
  const float* z            = (const float*)d_in[2];
  const int*   mask         = (const int*)  d_in[3];
  const float* attn_s_ln_g  = (const float*)d_in[4];
  const float* attn_gate_w  = (const float*)d_in[5];
  const float* attn_gate_b  = (const float*)d_in[6];
  const float* attn_skip_w  = (const float*)d_in[7];
  const float* wq           = (const float*)d_in[8];
  const float* bq           = (const float*)d_in[9];
  const float* wk           = (const float*)d_in[10];
  const float* wv           = (const float*)d_in[11];
  const float* z_ln_g       = (const float*)d_in[12];
  const float* z_ln_b       = (const float*)d_in[13];
  const float* wb           = (const float*)d_in[14];
  const float* wg           = (const float*)d_in[15];
  const float* wo           = (const float*)d_in[16];
  const float* attn_og_w    = (const float*)d_in[17];
  const float* attn_og_b    = (const float*)d_in[18];
  const float* tr_s_ln_g    = (const float*)d_in[19];
  const float* tr_gate_w    = (const float*)d_in[20];
  const float* tr_gate_b    = (const float*)d_in[21];
  const float* tr_skip_w    = (const float*)d_in[22];
  const float* tr_w1        = (const float*)d_in[23];
  const float* tr_w2        = (const float*)d_in[24];
  const float* tr_wo        = (const float*)d_in[25];
  const float* tr_og_w      = (const float*)d_in[26];
  const float* tr_og_b      = (const float*)d_in[27];

  char* wsb = (char*)d_ws;
  uint16_t* BTa   = (uint16_t*)(wsb + OFF_BT_ADA_ATTN);
  uint16_t* BTt   = (uint16_t*)(wsb + OFF_BT_ADA_TR);
  uint16_t* BTo   = (uint16_t*)(wsb + OFF_BT_OUTGATE);
  uint16_t* BTq   = (uint16_t*)(wsb + OFF_BT_QKVG);
  uint16_t* BTwo  = (uint16_t*)(wsb + OFF_BT_WO);
  uint16_t* BTw12 = (uint16_t*)(wsb + OFF_BT_W12);
  uint16_t* BTtw  = (uint16_t*)(wsb + OFF_BT_TRWO);
  uint16_t* WBGT  = (uint16_t*)(wsb + OFF_WBGT);
  float*    ZCOL  = (float*)   (wsb + OFF_ZCOL);
  float*    OGB   = (float*)   (wsb + OFF_OGB);
  uint16_t* SBF   = (uint16_t*)(wsb + OFF_SBF);
  uint16_t* SLNA  = (uint16_t*)(wsb + OFF_SLNA);
  uint16_t* SLNT  = (uint16_t*)(wsb + OFF_SLNT);
  float*    ALNRAW= (float*)   (wsb + OFF_ALNRAW);
  float*    GATEOUT=(float*)   (wsb + OFF_GATEOUT);
  float*    GS    = (float*)   (wsb + OFF_GS);
  uint16_t* ALNBF = (uint16_t*)(wsb + OFF_ALNBF);
  float*    QKVG  = (float*)   (wsb + OFF_QKVG);
  uint16_t* QP    = (uint16_t*)(wsb + OFF_QP);
  uint16_t* KP    = (uint16_t*)(wsb + OFF_KP);
  uint16_t* VT    = (uint16_t*)(wsb + OFF_VT);
  uint16_t* BIASB = (uint16_t*)(wsb + OFF_BIAS);
  uint16_t* SPB   = (uint16_t*)(wsb + OFF_SP);
  uint16_t* OBF   = (uint16_t*)(wsb + OFF_OBF);
  float*    AMID  = (float*)   (wsb + OFF_AMID);
  uint16_t* HIDBF = (uint16_t*)(wsb + OFF_BIAS);   // reuse (bias dead after logits)
  float*    OUTF  = (float*)d_out;

  // weight convert descriptors
  CvtArgs ca;
  const float* srcs[14] = {attn_gate_w, attn_skip_w, tr_gate_w, tr_skip_w,
                           attn_og_w, tr_og_w, wq, wk, wv, wg, wo, tr_w1, tr_w2, tr_wo};
  uint16_t* dsts[14] = {BTa, BTa + (size_t)768*384, BTt, BTt + (size_t)768*384,
                        BTo, BTo + (size_t)768*384,
                        BTq, BTq + (size_t)768*768, BTq + (size_t)2*768*768, BTq + (size_t)3*768*768,
                        BTwo, BTw12, BTw12 + (size_t)1536*768, BTtw};
  int Ks[14] = {384,384,384,384,384,384, 768,768,768,768,768, 768,768, 1536};
  int Ns[14] = {768,768,768,768,768,768, 768,768,768,768,768, 1536,1536, 768};
  int tiles[14] = {288,288,288,288,288,288, 576,576,576,576,576, 1152,1152, 1152};
  int pre = 0;
  for (int i = 0; i < 14; i++){
    ca.src[i] = srcs[i]; ca.dst[i] = dsts[i]; ca.K[i] = Ks[i]; ca.N[i] = Ns[i];
    ca.prefix[i] = pre; pre += tiles[i];
  }
  ca.prefix[14] = pre;  // 8064

  k_cvt<<<pre, 256, 0, stream>>>(ca);
  k_prep<<<770, 128, 0, stream>>>(s, attn_s_ln_g, tr_s_ln_g, attn_og_b, tr_og_b,
                                  z_ln_g, z_ln_b, wb, SBF, SLNA, SLNT, OGB, WBGT, ZCOL);
  k_ln768<<<768, 256, 0, stream>>>(a, ALNRAW);

  // gate_out = sigmoid(s @ [attn_og_w | tr_og_w] + ogb)
  k_gemm<<<dim3(24,12), 256, 0, stream>>>(SBF, BTo, 768, 1536, 384,
      GATEOUT, nullptr, 2, OGB, nullptr, 0, 0, nullptr, nullptr);
  // gs = sln_attn @ [gate_w | skip_w]
  k_gemm<<<dim3(24,12), 256, 0, stream>>>(SLNA, BTa, 768, 1536, 384,
      GS, nullptr, 0, nullptr, nullptr, 0, 0, nullptr, nullptr);
  k_adaln<<<576, 256, 0, stream>>>(GS, attn_gate_b, ALNRAW, ALNBF);
  // qkvg = a_ln @ [wq|wk|wv|wg]
  k_gemm<<<dim3(48,12), 256, 0, stream>>>(ALNBF, BTq, 768, 3072, 768,
      QKVG, nullptr, 0, nullptr, nullptr, 0, 0, nullptr, nullptr);

  k_zbias<<<dim3(12,768), 256, 0, stream>>>(z, WBGT, ZCOL, BIASB);
  k_trans<<<dim3(12,16), 256, 0, stream>>>(QKVG, bq, QP, KP, VT);
  k_logits<<<dim3(12,12,16), 256, 0, stream>>>(QP, KP, BIASB, mask, SPB);
  k_softmax<<<12288, 256, 0, stream>>>(SPB);
  k_pv<<<dim3(12,16), 256, 0, stream>>>(SPB, VT, QKVG, OBF);
  // a_mid = a + gate_attn * (o @ wo)
  k_gemm<<<dim3(12,12), 256, 0, stream>>>(OBF, BTwo, 768, 768, 768,
      AMID, nullptr, 5, nullptr, GATEOUT, 1536, 0, a, nullptr);

  k_ln768<<<768, 256, 0, stream>>>(AMID, ALNRAW);
  k_gemm<<<dim3(24,12), 256, 0, stream>>>(SLNT, BTt, 768, 1536, 384,
      GS, nullptr, 0, nullptr, nullptr, 0, 0, nullptr, nullptr);
  k_adaln<<<576, 256, 0, stream>>>(GS, tr_gate_b, ALNRAW, ALNBF);
  // h12 = t_ln @ [w1|w2]  (reuses QKVG buffer)
  k_gemm<<<dim3(48,12), 256, 0, stream>>>(ALNBF, BTw12, 768, 3072, 768,
      QKVG, nullptr, 0, nullptr, nullptr, 0, 0, nullptr, nullptr);
  k_silu<<<1152, 256, 0, stream>>>(QKVG, HIDBF);
  // out = a_mid + mask * gate_tr * (hid @ tr_wo)
  k_gemm<<<dim3(12,12), 256, 0, stream>>>(HIDBF, BTtw, 768, 768, 1536,
      OUTF, nullptr, 4, nullptr, GATEOUT, 1536, 768, AMID, mask);
}

// Round 3
// 635.286 us; speedup vs baseline: 1.0744x; 1.0744x over previous
//
#include <hip/hip_runtime.h>
#include <hip/hip_bf16.h>
#include <stdint.h>

// B=1, N=768, C_A=768, C_S=384, C_Z=128, H=16, C_HID=48, N_TRANS=2

typedef __bf16 bf16x8 __attribute__((ext_vector_type(8)));
typedef float  f32x4  __attribute__((ext_vector_type(4)));

#define DEVI __device__ __forceinline__

DEVI uint16_t f2b(float f){ __hip_bfloat16 h = __float2bfloat16(f); return __builtin_bit_cast(uint16_t, h); }
DEVI float    b2f(uint16_t u){ return __bfloat162float(__builtin_bit_cast(__hip_bfloat16, u)); }
DEVI float    sigm(float x){ return 1.0f/(1.0f + __expf(-x)); }

DEVI f32x4 MFMA(uint4 a, uint4 b, f32x4 c){
  return __builtin_amdgcn_mfma_f32_16x16x32_bf16(
      __builtin_bit_cast(bf16x8, a), __builtin_bit_cast(bf16x8, b), c, 0, 0, 0);
}

// async global->LDS, 16B per lane; lds dest = wave-uniform base + lane*16
DEVI void glds16(const void* g, void* l){
  __builtin_amdgcn_global_load_lds(
      (const __attribute__((address_space(1))) void*)g,
      (__attribute__((address_space(3))) void*)l, 16, 0, 0);
}

// ---------------- workspace layout ----------------
constexpr size_t SZ_BT_ADA   = (size_t)1536*384*2;
constexpr size_t OFF_BT_ADA_ATTN = 0;
constexpr size_t OFF_BT_ADA_TR   = OFF_BT_ADA_ATTN + SZ_BT_ADA;
constexpr size_t OFF_BT_OUTGATE  = OFF_BT_ADA_TR   + SZ_BT_ADA;
constexpr size_t OFF_BT_QKVG     = OFF_BT_OUTGATE  + SZ_BT_ADA;
constexpr size_t OFF_BT_WO       = OFF_BT_QKVG + (size_t)3072*768*2;
constexpr size_t OFF_BT_W12      = OFF_BT_WO   + (size_t)768*768*2;
constexpr size_t OFF_BT_TRWO     = OFF_BT_W12  + (size_t)3072*768*2;
constexpr size_t OFF_WBGT        = OFF_BT_TRWO + (size_t)768*1536*2;
constexpr size_t OFF_ZCOL        = OFF_WBGT + 4096;
constexpr size_t OFF_OGB         = OFF_ZCOL + 256;
constexpr size_t OFF_SBF         = OFF_OGB + 6144;
constexpr size_t OFF_SLNA        = OFF_SBF  + (size_t)768*384*2;
constexpr size_t OFF_SLNT        = OFF_SLNA + (size_t)768*384*2;
constexpr size_t OFF_GATEOUT     = OFF_SLNT + (size_t)768*384*2;
constexpr size_t OFF_GS          = OFF_GATEOUT + (size_t)768*1536*4;
constexpr size_t OFF_ALNBF       = OFF_GS + (size_t)768*1536*4;
constexpr size_t OFF_QKVGB       = OFF_ALNBF + (size_t)768*768*2;   // bf16 [768][3072]
constexpr size_t OFF_QP          = OFF_QKVGB + (size_t)768*3072*2;
constexpr size_t OFF_KP          = OFF_QP + (size_t)16*768*64*2;
constexpr size_t OFF_VT          = OFF_KP + (size_t)16*768*64*2;
constexpr size_t OFF_BIAS        = OFF_VT + (size_t)16*64*768*2;    // reused as hid_bf16 later
constexpr size_t OFF_OBF         = OFF_BIAS + (size_t)16*768*768*2;
constexpr size_t OFF_AMID        = OFF_OBF + (size_t)768*768*2;

// ---------------- weight transpose/convert fp32 -> bf16 B^T ----------------
struct CvtArgs {
  const float* src[14];
  uint16_t*    dst[14];
  int K[14], N[14];
  int prefix[15];
};

__global__ __launch_bounds__(256) void k_cvt(CvtArgs a){
  int bid = blockIdx.x;
  int ti = 0;
  while (ti < 13 && bid >= a.prefix[ti+1]) ti++;
  int local = bid - a.prefix[ti];
  int K = a.K[ti], N = a.N[ti];
  int tN = N >> 5;
  int n0 = (local % tN) << 5, k0 = (local / tN) << 5;
  __shared__ float lds[32][33];
  const float* src = a.src[ti];
  uint16_t* dst = a.dst[ti];
  int t = threadIdx.x;
  int c = t & 31, r0 = t >> 5;
  #pragma unroll
  for (int i = 0; i < 4; i++){
    int kk = r0 + 8*i;
    lds[kk][c] = src[(size_t)(k0+kk)*N + n0 + c];
  }
  __syncthreads();
  #pragma unroll
  for (int i = 0; i < 4; i++){
    int nn = r0 + 8*i;
    dst[(size_t)(n0+nn)*K + k0 + c] = f2b(lds[c][nn]);
  }
}

// ---------------- prep: LN(s), gate-bias concat, wb*g prep ----------------
__global__ __launch_bounds__(128) void k_prep(
    const float* s, const float* g_attn, const float* g_tr,
    const float* attn_ogb, const float* tr_ogb,
    const float* z_g, const float* z_b, const float* wb,
    uint16_t* s_bf, uint16_t* sln_a, uint16_t* sln_t,
    float* ogb, uint16_t* wbgt, float* zcol)
{
  int b = blockIdx.x, t = threadIdx.x;
  if (b < 768){
    const float* row = s + (size_t)b*384;
    float x0 = row[t], x1 = row[t+128], x2 = row[t+256];
    float sm = x0+x1+x2, sq = x0*x0+x1*x1+x2*x2;
    #pragma unroll
    for (int off = 32; off; off >>= 1){ sm += __shfl_xor(sm, off, 64); sq += __shfl_xor(sq, off, 64); }
    __shared__ float rs_[2], rq_[2];
    int w = t >> 6;
    if ((t & 63) == 0){ rs_[w] = sm; rq_[w] = sq; }
    __syncthreads();
    float S = rs_[0]+rs_[1], Q = rq_[0]+rq_[1];
    float mu = S * (1.f/384.f);
    float var = Q * (1.f/384.f) - mu*mu;
    float rstd = rsqrtf(var + 1e-5f);
    float xs[3] = {x0, x1, x2};
    #pragma unroll
    for (int i = 0; i < 3; i++){
      int ci = t + 128*i;
      float ln = (xs[i] - mu) * rstd;
      s_bf [(size_t)b*384 + ci] = f2b(xs[i]);
      sln_a[(size_t)b*384 + ci] = f2b(ln * g_attn[ci]);
      sln_t[(size_t)b*384 + ci] = f2b(ln * g_tr[ci]);
    }
  } else if (b == 768){
    for (int i = t; i < 1536; i += 128)
      ogb[i] = (i < 768) ? attn_ogb[i] : tr_ogb[i-768];
  } else {
    for (int i = t; i < 2048; i += 128){
      int h = i >> 7, c = i & 127;
      wbgt[i] = f2b(z_g[c] * wb[c*16 + h]);
    }
    if (t < 16){
      float cs = 0.f, cn = 0.f;
      for (int c = 0; c < 128; c++){ cs += z_g[c]*wb[c*16+t]; cn += z_b[c]*wb[c*16+t]; }
      zcol[t] = cs; zcol[16+t] = cn;
    }
  }
}

// ---------------- fused LN(768) + adaLN combine -> bf16 ----------------
// out = sigmoid(gs[:, :768]+gb) * LN(asrc) + gs[:, 768:]
__global__ __launch_bounds__(256) void k_adaln2(
    const float* __restrict__ asrc, const float* __restrict__ gs,
    const float* __restrict__ gb, uint16_t* __restrict__ out)
{
  int b = blockIdx.x, t = threadIdx.x;
  const float* row = asrc + (size_t)b*768;
  float x0 = row[t], x1 = row[t+256], x2 = row[t+512];
  float sm = x0+x1+x2, sq = x0*x0+x1*x1+x2*x2;
  #pragma unroll
  for (int off = 32; off; off >>= 1){ sm += __shfl_xor(sm, off, 64); sq += __shfl_xor(sq, off, 64); }
  __shared__ float rs_[4], rq_[4];
  int w = t >> 6;
  if ((t & 63) == 0){ rs_[w] = sm; rq_[w] = sq; }
  __syncthreads();
  float S = rs_[0]+rs_[1]+rs_[2]+rs_[3], Q = rq_[0]+rq_[1]+rq_[2]+rq_[3];
  float mu = S*(1.f/768.f), var = Q*(1.f/768.f) - mu*mu, rstd = rsqrtf(var + 1e-5f);
  float xs[3] = {x0, x1, x2};
  #pragma unroll
  for (int i = 0; i < 3; i++){
    int c = t + 256*i;
    float g  = gs[(size_t)b*1536 + c];
    float sk = gs[(size_t)b*1536 + 768 + c];
    out[(size_t)b*768 + c] = f2b(sigm(g + gb[c]) * ((xs[i]-mu)*rstd) + sk);
  }
}

// ---------------- bf16 MFMA GEMM, m97-style: BK=64, global_load_lds, XOR-swizzle ----
// C = A[MxK] * B, B given as BT[NxK]. 64x64 tile / block, 4 waves.
// modes: 0 fp32 out, 1 bf16 out, 2 sigmoid(x+bias[col]) fp32,
//        4 resid + mask[row]*gate*x (fp32), 5 resid + gate*x (fp32)
__global__ __launch_bounds__(256) void k_gemm(
    const uint16_t* __restrict__ A, const uint16_t* __restrict__ BT,
    int M, int N, int K,
    float* outF, uint16_t* outB, int mode,
    const float* bias, const float* gate, int gateLd, int gateOff,
    const float* resid, const int* mask)
{
  __shared__ uint16_t As[64*64], Bs[64*64];   // 8 KB each, chunk-swizzled
  int t = threadIdx.x;
  int n0 = blockIdx.x*64, m0 = blockIdx.y*64;
  int w = t >> 6, lane = t & 63, mm = lane & 15, q = lane >> 4;
  // staging: 2 global_load_lds per buffer per thread; LDS = base(wave,instr) + lane*16
  int fc0 = 128*w + lane, fc1 = fc0 + 64;     // flat 16B-chunk indices
  int r0 = fc0 >> 3, c0 = (fc0 & 7) ^ (r0 & 7);
  int r1 = fc1 >> 3, c1 = (fc1 & 7) ^ (r1 & 7);
  const uint16_t* gA0 = A  + (size_t)(m0 + r0)*K + c0*8;
  const uint16_t* gA1 = A  + (size_t)(m0 + r1)*K + c1*8;
  const uint16_t* gB0 = BT + (size_t)(n0 + r0)*K + c0*8;
  const uint16_t* gB1 = BT + (size_t)(n0 + r1)*K + c1*8;
  uint16_t* lA0 = As + (2*w + 0)*512;
  uint16_t* lA1 = As + (2*w + 1)*512;
  uint16_t* lB0 = Bs + (2*w + 0)*512;
  uint16_t* lB1 = Bs + (2*w + 1)*512;
  f32x4 zz = {0.f,0.f,0.f,0.f};
  f32x4 acc[4] = {zz, zz, zz, zz};
  int sw = mm & 7;
  for (int k0 = 0; k0 < K; k0 += 64){
    __syncthreads();                 // prior reads done before overwrite
    glds16(gA0 + k0, lA0);
    glds16(gA1 + k0, lA1);
    glds16(gB0 + k0, lB0);
    glds16(gB1 + k0, lB1);
    __syncthreads();                 // vmcnt(0) drained before barrier
    #pragma unroll
    for (int kc = 0; kc < 2; kc++){
      uint4 av = *(const uint4*)&As[(16*w + mm)*64 + ((kc*4 + q) ^ sw)*8];
      #pragma unroll
      for (int j = 0; j < 4; j++){
        uint4 bv = *(const uint4*)&Bs[(16*j + mm)*64 + ((kc*4 + q) ^ sw)*8];
        acc[j] = MFMA(av, bv, acc[j]);
      }
    }
  }
  #pragma unroll
  for (int j = 0; j < 4; j++){
    #pragma unroll
    for (int rr = 0; rr < 4; rr++){
      int row = m0 + 16*w + q*4 + rr;
      int col = n0 + 16*j + mm;
      float v = acc[j][rr];
      size_t oi = (size_t)row*N + col;
      if (mode == 0)      outF[oi] = v;
      else if (mode == 1) outB[oi] = f2b(v);
      else if (mode == 2) outF[oi] = sigm(v + bias[col]);
      else if (mode == 5) outF[oi] = resid[oi] + gate[(size_t)row*gateLd + gateOff + col]*v;
      else {
        float mf = (float)mask[row];
        outF[oi] = resid[oi] + mf * gate[(size_t)row*gateLd + gateOff + col] * v;
      }
    }
  }
}

// ---------------- z -> pair bias ----------------
__global__ __launch_bounds__(256) void k_zbias(
    const float* __restrict__ z, const uint16_t* __restrict__ wbgt_g,
    const float* __restrict__ zcol, uint16_t* __restrict__ bias_g)
{
  __shared__ uint16_t zb[64*128];
  __shared__ uint16_t wbt[16*128];
  __shared__ float mu_s[64], rs_s[64];
  __shared__ uint16_t Sout[16*72];
  int t = threadIdx.x;
  size_t P0 = (size_t)blockIdx.y*768 + (size_t)blockIdx.x*64;
  ((uint4*)wbt)[t] = ((const uint4*)wbgt_g)[t];   // 256 uint4 = full 16x128 bf16
  int p = t >> 2, qq = t & 3;
  const float4* zp = (const float4*)(z + (P0 + p)*128) + qq*8;
  float s1 = 0.f, s2 = 0.f;
  uint32_t lb[16];
  #pragma unroll
  for (int it = 0; it < 8; it++){
    float4 v = zp[it];
    s1 += v.x + v.y + v.z + v.w;
    s2 += v.x*v.x + v.y*v.y + v.z*v.z + v.w*v.w;
    lb[2*it]   = (uint32_t)f2b(v.x) | ((uint32_t)f2b(v.y) << 16);
    lb[2*it+1] = (uint32_t)f2b(v.z) | ((uint32_t)f2b(v.w) << 16);
  }
  uint4* zb4 = (uint4*)zb;
  #pragma unroll
  for (int kk = 0; kk < 4; kk++)
    zb4[p*16 + qq*4 + kk] = ((uint4*)lb)[kk];
  s1 += __shfl_xor(s1, 1, 64); s1 += __shfl_xor(s1, 2, 64);
  s2 += __shfl_xor(s2, 1, 64); s2 += __shfl_xor(s2, 2, 64);
  if (qq == 0){
    float mu = s1 * (1.f/128.f);
    mu_s[p] = mu;
    rs_s[p] = rsqrtf(s2*(1.f/128.f) - mu*mu + 1e-5f);
  }
  __syncthreads();
  int w = t >> 6, lane = t & 63, hh = lane & 15, q = lane >> 4;
  float cs = zcol[hh], cn = zcol[16 + hh];
  f32x4 acc = {0.f, 0.f, 0.f, 0.f};
  const uint4* wbt4 = (const uint4*)wbt;
  #pragma unroll
  for (int kc = 0; kc < 4; kc++){
    uint4 av = zb4[(16*w + hh)*16 + kc*4 + q];
    uint4 bv = wbt4[hh*16 + kc*4 + q];
    acc = MFMA(av, bv, acc);
  }
  #pragma unroll
  for (int rr = 0; rr < 4; rr++){
    int pl = 16*w + q*4 + rr;
    float val = rs_s[pl]*(acc[rr] - mu_s[pl]*cs) + cn;
    Sout[hh*72 + pl] = f2b(val);
  }
  __syncthreads();
  int h2 = t >> 4, p2 = (t & 15)*4;
  uint2 v2 = *(uint2*)&Sout[h2*72 + p2];
  *(uint2*)(bias_g + (size_t)h2*589824 + P0 + p2) = v2;
}

// ---------------- split qkvg(bf16) -> q,k [h][n][64], v^T [h][64][n] ----------------
__global__ __launch_bounds__(256) void k_trans(
    const uint16_t* __restrict__ qkvg, const float* __restrict__ bq,
    uint16_t* qp, uint16_t* kp, uint16_t* vt)
{
  int h = blockIdx.y, n0 = blockIdx.x*64, t = threadIdx.x;
  __shared__ uint16_t vbuf[64*72];
  int c = t & 63, r0 = t >> 6;
  const float scale = 0.14433756729740643f;  // 1/sqrt(48)
  for (int r = r0; r < 64; r += 4){
    size_t base = (size_t)(n0 + r)*3072;
    float qv = 0.f, kv = 0.f, vv = 0.f;
    if (c < 48){
      int cc = h*48 + c;
      qv = (b2f(qkvg[base + cc]) + bq[cc]) * scale;
      kv = b2f(qkvg[base + 768 + cc]);
      vv = b2f(qkvg[base + 1536 + cc]);
    }
    size_t oi = ((size_t)h*768 + n0 + r)*64 + c;
    qp[oi] = f2b(qv);
    kp[oi] = f2b(kv);
    vbuf[c*72 + r] = f2b(vv);
  }
  __syncthreads();
  int cc = t >> 2, rb = (t & 3)*16;
  uint16_t* dst = vt + ((size_t)h*64 + cc)*768 + n0 + rb;
  *(uint4*)dst       = *(uint4*)&vbuf[cc*72 + rb];
  *(uint4*)(dst + 8) = *(uint4*)&vbuf[cc*72 + rb + 8];
}

// ---------------- fused flash attention per (q-tile, head) ----------------
// logits = qk^T + bias + maskterm; online softmax; o = P.v; out = o * sigmoid(g)
__global__ __launch_bounds__(256) void k_flash(
    const uint16_t* __restrict__ qp, const uint16_t* __restrict__ kp,
    const uint16_t* __restrict__ vt, const uint16_t* __restrict__ bias_g,
    const uint16_t* __restrict__ qkvg, const int* __restrict__ mask,
    uint16_t* __restrict__ obf)
{
  __shared__ uint16_t Qs[64*72], Ks[64*72], Vs[64*72], Ps[64*72];
  __shared__ float mk[768];
  int t = threadIdx.x;
  int q0 = blockIdx.x*64, h = blockIdx.y;
  int w = t >> 6, lane = t & 63, mm = lane & 15, q = lane >> 4;
  // stage Q tile + mask
  {
    int row = t >> 2, c = t & 3;
    const uint4* src = (const uint4*)(qp + ((size_t)h*768 + q0 + row)*64) + c*2;
    *(uint4*)&Qs[row*72 + c*16]     = src[0];
    *(uint4*)&Qs[row*72 + c*16 + 8] = src[1];
    mk[t] = (float)mask[t]; mk[t+256] = (float)mask[t+256]; mk[t+512] = (float)mask[t+512];
  }
  f32x4 zz = {0.f,0.f,0.f,0.f};
  f32x4 o0 = zz, o1 = zz, o2 = zz;
  f32x4 m_i = {-1e30f,-1e30f,-1e30f,-1e30f};
  f32x4 l_i = zz;
  const uint16_t* bias_h = bias_g + (size_t)h*589824;
  for (int kt = 0; kt < 12; kt++){
    __syncthreads();   // Qs staged (first iter) / prior-tile Ks,Vs,Ps reads done
    {
      int row = t >> 2, c = t & 3;
      const uint4* ks = (const uint4*)(kp + ((size_t)h*768 + kt*64 + row)*64) + c*2;
      *(uint4*)&Ks[row*72 + c*16]     = ks[0];
      *(uint4*)&Ks[row*72 + c*16 + 8] = ks[1];
      const uint4* vs = (const uint4*)(vt + ((size_t)h*64 + row)*768 + kt*64) + c*2;
      *(uint4*)&Vs[row*72 + c*16]     = vs[0];
      *(uint4*)&Vs[row*72 + c*16 + 8] = vs[1];
    }
    __syncthreads();
    // S = Q K^T
    f32x4 s[4] = {zz, zz, zz, zz};
    #pragma unroll
    for (int kc = 0; kc < 2; kc++){
      uint4 av = *(const uint4*)&Qs[(16*w + mm)*72 + kc*32 + q*8];
      #pragma unroll
      for (int j = 0; j < 4; j++){
        uint4 bv = *(const uint4*)&Ks[(16*j + mm)*72 + kc*32 + q*8];
        s[j] = MFMA(av, bv, s[j]);
      }
    }
    // + bias + mask
    int srow = q0 + 16*w + q*4;
    #pragma unroll
    for (int j = 0; j < 4; j++){
      int scol = kt*64 + 16*j + mm;
      float mt = (mk[scol] - 1.f)*1e9f;
      #pragma unroll
      for (int rr = 0; rr < 4; rr++)
        s[j][rr] += b2f(bias_h[(size_t)(srow+rr)*768 + scol]) + mt;
    }
    // online softmax
    f32x4 tm = s[0];
    #pragma unroll
    for (int j = 1; j < 4; j++)
      #pragma unroll
      for (int rr = 0; rr < 4; rr++) tm[rr] = fmaxf(tm[rr], s[j][rr]);
    #pragma unroll
    for (int off = 1; off < 16; off <<= 1)
      #pragma unroll
      for (int rr = 0; rr < 4; rr++) tm[rr] = fmaxf(tm[rr], __shfl_xor(tm[rr], off, 64));
    f32x4 mnew, alpha, rsum = zz;
    #pragma unroll
    for (int rr = 0; rr < 4; rr++){
      mnew[rr] = fmaxf(m_i[rr], tm[rr]);
      alpha[rr] = __expf(m_i[rr] - mnew[rr]);
    }
    #pragma unroll
    for (int j = 0; j < 4; j++)
      #pragma unroll
      for (int rr = 0; rr < 4; rr++){
        s[j][rr] = __expf(s[j][rr] - mnew[rr]);
        rsum[rr] += s[j][rr];
      }
    #pragma unroll
    for (int off = 1; off < 16; off <<= 1)
      #pragma unroll
      for (int rr = 0; rr < 4; rr++) rsum[rr] += __shfl_xor(rsum[rr], off, 64);
    #pragma unroll
    for (int rr = 0; rr < 4; rr++){
      l_i[rr] = l_i[rr]*alpha[rr] + rsum[rr];
      o0[rr] *= alpha[rr]; o1[rr] *= alpha[rr]; o2[rr] *= alpha[rr];
      m_i[rr] = mnew[rr];
    }
    // write P to LDS (C-layout -> A-layout transform)
    #pragma unroll
    for (int j = 0; j < 4; j++)
      #pragma unroll
      for (int rr = 0; rr < 4; rr++)
        Ps[(16*w + q*4 + rr)*72 + 16*j + mm] = f2b(s[j][rr]);
    __syncthreads();
    // O += P V
    #pragma unroll
    for (int kc = 0; kc < 2; kc++){
      uint4 av = *(const uint4*)&Ps[(16*w + mm)*72 + kc*32 + q*8];
      uint4 bv0 = *(const uint4*)&Vs[(mm)*72      + kc*32 + q*8];
      uint4 bv1 = *(const uint4*)&Vs[(16+mm)*72   + kc*32 + q*8];
      uint4 bv2 = *(const uint4*)&Vs[(32+mm)*72   + kc*32 + q*8];
      o0 = MFMA(av, bv0, o0);
      o1 = MFMA(av, bv1, o1);
      o2 = MFMA(av, bv2, o2);
    }
  }
  // epilogue: normalize, gate, store
  f32x4 inv;
  #pragma unroll
  for (int rr = 0; rr < 4; rr++) inv[rr] = 1.f / l_i[rr];
  #pragma unroll
  for (int j = 0; j < 3; j++){
    f32x4 ov = (j == 0) ? o0 : (j == 1) ? o1 : o2;
    int col = 16*j + mm;
    #pragma unroll
    for (int rr = 0; rr < 4; rr++){
      int row = q0 + 16*w + q*4 + rr;
      float g = b2f(qkvg[(size_t)row*3072 + 2304 + h*48 + col]);
      obf[(size_t)row*768 + h*48 + col] = f2b(ov[rr]*inv[rr]*sigm(g));
    }
  }
}

// ---------------- SwiGLU: silu(h1)*h2 -> bf16 (bf16 input) ----------------
__global__ __launch_bounds__(256) void k_silu(const uint16_t* __restrict__ h12, uint16_t* __restrict__ hid){
  int idx4 = blockIdx.x*256 + threadIdx.x;
  int row = idx4 / 384;
  int c4 = (idx4 % 384)*4;
  const uint16_t* p1 = h12 + (size_t)row*3072 + c4;
  const uint16_t* p2 = p1 + 1536;
  uint16_t o[4];
  #pragma unroll
  for (int i = 0; i < 4; i++){
    float x1 = b2f(p1[i]), x2 = b2f(p2[i]);
    o[i] = f2b(x1*sigm(x1)*x2);
  }
  *(uint2*)(hid + (size_t)row*1536 + c4) = *(uint2*)o;
}

// ---------------- host launcher ----------------
extern "C" void kernel_launch(void* const* d_in, const int* in_sizes, int n_in,
                              void* d_out, int out_size, void* d_ws, size_t ws_size,
                              hipStream_t stream)
{
  const float* a            = (const float*)d_in[0];
  const float* s            = (const float*)d_in[1];
  const float* z            = (const float*)d_in[2];
  const int*   mask         = (const int*)  d_in[3];
  const float* attn_s_ln_g  = (const float*)d_in[4];
  const float* attn_gate_w  = (const float*)d_in[5];
  const float* attn_gate_b  = (const float*)d_in[6];
  const float* attn_skip_w  = (const float*)d_in[7];
  const float* wq           = (const float*)d_in[8];
  const float* bq           = (const float*)d_in[9];
  const float* wk           = (const float*)d_in[10];
  const float* wv           = (const float*)d_in[11];
  const float* z_ln_g       = (const float*)d_in[12];
  const float* z_ln_b       = (const float*)d_in[13];
  const float* wb           = (const float*)d_in[14];
  const float* wg           = (const float*)d_in[15];
  const float* wo           = (const float*)d_in[16];
  const float* attn_og_w    = (const float*)d_in[17];
  const float* attn_og_b    = (const float*)d_in[18];
  const float* tr_s_ln_g    = (const float*)d_in[19];
  const float* tr_gate_w    = (const float*)d_in[20];
  const float* tr_gate_b    = (const float*)d_in[21];
  const float* tr_skip_w    = (const float*)d_in[22];
  const float* tr_w1        = (const float*)d_in[23];
  const float* tr_w2        = (const float*)d_in[24];
  const float* tr_wo        = (const float*)d_in[25];
  const float* tr_og_w      = (const float*)d_in[26];
  const float* tr_og_b      = (const float*)d_in[27];

  char* wsb = (char*)d_ws;
  uint16_t* BTa   = (uint16_t*)(wsb + OFF_BT_ADA_ATTN);
  uint16_t* BTt   = (uint16_t*)(wsb + OFF_BT_ADA_TR);
  uint16_t* BTo   = (uint16_t*)(wsb + OFF_BT_OUTGATE);
  uint16_t* BTq   = (uint16_t*)(wsb + OFF_BT_QKVG);
  uint16_t* BTwo  = (uint16_t*)(wsb + OFF_BT_WO);
  uint16_t* BTw12 = (uint16_t*)(wsb + OFF_BT_W12);
  uint16_t* BTtw  = (uint16_t*)(wsb + OFF_BT_TRWO);
  uint16_t* WBGT  = (uint16_t*)(wsb + OFF_WBGT);
  float*    ZCOL  = (float*)   (wsb + OFF_ZCOL);
  float*    OGB   = (float*)   (wsb + OFF_OGB);
  uint16_t* SBF   = (uint16_t*)(wsb + OFF_SBF);
  uint16_t* SLNA  = (uint16_t*)(wsb + OFF_SLNA);
  uint16_t* SLNT  = (uint16_t*)(wsb + OFF_SLNT);
  float*    GATEOUT=(float*)   (wsb + OFF_GATEOUT);
  float*    GS    = (float*)   (wsb + OFF_GS);
  uint16_t* ALNBF = (uint16_t*)(wsb + OFF_ALNBF);
  uint16_t* QKVGB = (uint16_t*)(wsb + OFF_QKVGB);
  uint16_t* QP    = (uint16_t*)(wsb + OFF_QP);
  uint16_t* KP    = (uint16_t*)(wsb + OFF_KP);
  uint16_t* VT    = (uint16_t*)(wsb + OFF_VT);
  uint16_t* BIASB = (uint16_t*)(wsb + OFF_BIAS);
  uint16_t* OBF   = (uint16_t*)(wsb + OFF_OBF);
  float*    AMID  = (float*)   (wsb + OFF_AMID);
  uint16_t* HIDBF = (uint16_t*)(wsb + OFF_BIAS);   // reuse (bias dead after flash)
  float*    OUTF  = (float*)d_out;

  CvtArgs ca;
  const float* srcs[14] = {attn_gate_w, attn_skip_w, tr_gate_w, tr_skip_w,
                           attn_og_w, tr_og_w, wq, wk, wv, wg, wo, tr_w1, tr_w2, tr_wo};
  uint16_t* dsts[14] = {BTa, BTa + (size_t)768*384, BTt, BTt + (size_t)768*384,
                        BTo, BTo + (size_t)768*384,
                        BTq, BTq + (size_t)768*768, BTq + (size_t)2*768*768, BTq + (size_t)3*768*768,
                        BTwo, BTw12, BTw12 + (size_t)1536*768, BTtw};
  int Ks[14] = {384,384,384,384,384,384, 768,768,768,768,768, 768,768, 1536};
  int Ns[14] = {768,768,768,768,768,768, 768,768,768,768,768, 1536,1536, 768};
  int tiles[14] = {288,288,288,288,288,288, 576,576,576,576,576, 1152,1152, 1152};
  int pre = 0;
  for (int i = 0; i < 14; i++){
    ca.src[i] = srcs[i]; ca.dst[i] = dsts[i]; ca.K[i] = Ks[i]; ca.N[i] = Ns[i];
    ca.prefix[i] = pre; pre += tiles[i];
  }
  ca.prefix[14] = pre;

  k_cvt<<<pre, 256, 0, stream>>>(ca);
  k_prep<<<770, 128, 0, stream>>>(s, attn_s_ln_g, tr_s_ln_g, attn_og_b, tr_og_b,
                                  z_ln_g, z_ln_b, wb, SBF, SLNA, SLNT, OGB, WBGT, ZCOL);

  // gate_out = sigmoid(s @ [attn_og_w | tr_og_w] + ogb)
  k_gemm<<<dim3(24,12), 256, 0, stream>>>(SBF, BTo, 768, 1536, 384,
      GATEOUT, nullptr, 2, OGB, nullptr, 0, 0, nullptr, nullptr);
  // gs = sln_attn @ [gate_w | skip_w]
  k_gemm<<<dim3(24,12), 256, 0, stream>>>(SLNA, BTa, 768, 1536, 384,
      GS, nullptr, 0, nullptr, nullptr, 0, 0, nullptr, nullptr);
  k_adaln2<<<768, 256, 0, stream>>>(a, GS, attn_gate_b, ALNBF);
  // qkvg = a_ln @ [wq|wk|wv|wg]  (bf16 out)
  k_gemm<<<dim3(48,12), 256, 0, stream>>>(ALNBF, BTq, 768, 3072, 768,
      nullptr, QKVGB, 1, nullptr, nullptr, 0, 0, nullptr, nullptr);

  k_zbias<<<dim3(12,768), 256, 0, stream>>>(z, WBGT, ZCOL, BIASB);
  k_trans<<<dim3(12,16), 256, 0, stream>>>(QKVGB, bq, QP, KP, VT);
  k_flash<<<dim3(12,16), 256, 0, stream>>>(QP, KP, VT, BIASB, QKVGB, mask, OBF);
  // a_mid = a + gate_attn * (o @ wo)
  k_gemm<<<dim3(12,12), 256, 0, stream>>>(OBF, BTwo, 768, 768, 768,
      AMID, nullptr, 5, nullptr, GATEOUT, 1536, 0, a, nullptr);

  k_gemm<<<dim3(24,12), 256, 0, stream>>>(SLNT, BTt, 768, 1536, 384,
      GS, nullptr, 0, nullptr, nullptr, 0, 0, nullptr, nullptr);
  k_adaln2<<<768, 256, 0, stream>>>(AMID, GS, tr_gate_b, ALNBF);
  // h12 = t_ln @ [w1|w2]  (bf16 out, reuses QKVGB)
  k_gemm<<<dim3(48,12), 256, 0, stream>>>(ALNBF, BTw12, 768, 3072, 768,
      nullptr, QKVGB, 1, nullptr, nullptr, 0, 0, nullptr, nullptr);
  k_silu<<<1152, 256, 0, stream>>>(QKVGB, HIDBF);
  // out = a_mid + mask * gate_tr * (hid @ tr_wo)
  k_gemm<<<dim3(12,12), 256, 0, stream>>>(HIDBF, BTtw, 768, 768, 1536,
      OUTF, nullptr, 4, nullptr, GATEOUT, 1536, 768, AMID, mask);
}